// Round 7
// baseline (96.205 us; speedup 1.0000x reference)
//
#include <hip/hip_runtime.h>
#include <math.h>

typedef _Float16 f16x8 __attribute__((ext_vector_type(8)));
typedef float f32x4 __attribute__((ext_vector_type(4)));
typedef unsigned int u32;
typedef unsigned long long u64;

#define NBATCH 32
#define CIN    64
#define COUT   192
#define HWD    56
#define KR     4
#define NKQ    14

// ---- LDS map (dynamic, 79872 B total; 2 blocks/CU) ----
// WIN  [0, 36864)        : 768 items * 6 krows * 8B window table (persistent)
// EH   [36864, 46080)    : 72 rows * 128B fp16 E (single plane)
// EL   [46080, 55296)    : dual-plane only
// B    single: [46080, 70656) = 2 * 12288 ; dual: [55296, 79872)
// RAW  [36864, ~62990)   : staging overlay (stride 68), dead before E/B use
#define WINOFF 0
#define EHOFF  36864
#define ELOFF  46080
#define RAWOFF 36864
#define RAWSTR 68
#define LDS_TOTAL 79872

#define WS_BT_OFF 0
#define WS_W_OFF  1024

#define SBAR()   do { __builtin_amdgcn_s_barrier(); asm volatile("" ::: "memory"); } while(0)
#define WAITL()  asm volatile("s_waitcnt lgkmcnt(0)" ::: "memory")
#define WAITV0() asm volatile("s_waitcnt vmcnt(0)" ::: "memory")
#define WAITVL0() asm volatile("s_waitcnt vmcnt(0) lgkmcnt(0)" ::: "memory")

// ---------------- Kernel 1: wave-parallel Householder QR (f64) + fp16-range flag ----------------
__device__ __forceinline__ double wsum(double v) {
    #pragma unroll
    for (int m = 32; m >= 1; m >>= 1) v += __shfl_xor(v, m);
    return v;
}

__global__ void compute_bt_kernel(float* __restrict__ bt) {
    const int lane = threadIdx.x;
    const double ATd[5][7] = {
        {1,1,1,1,1,1,0},{0,1,-1,2,-2,3,0},{0,1,1,4,4,9,0},{0,1,-1,8,-8,27,0},{0,1,1,16,16,81,1}};
    const double pts[6] = {0.0,1.0,-1.0,2.0,-2.0,3.0};

    double Mr[7], Tr[7];
    #pragma unroll
    for (int c = 0; c < 7; ++c) { Mr[c] = 0.0; Tr[c] = 0.0; }
    if (lane < 15) {
        const int p = lane / 5, u = lane % 5;
        #pragma unroll
        for (int v = 0; v < 7; ++v) {
            double gg = (v < 6) ? ((p == 0) ? 1.0 : (p == 1) ? pts[v] : pts[v]*pts[v])
                                : ((p == 2) ? 1.0 : 0.0);
            Mr[v] = ATd[u][v] * gg;
        }
        #pragma unroll
        for (int c = 0; c < 7; ++c) Tr[c] = (c == u + p) ? 1.0 : 0.0;
    }

    #pragma unroll
    for (int j = 0; j < 7; ++j) {
        double mj = Mr[j];
        double sig = wsum((lane >= j && lane < 15) ? mj*mj : 0.0);
        double nrm = sqrt(sig);
        double ajj = __shfl(Mr[j], j);
        double alpha = (ajj > 0.0) ? -nrm : nrm;
        double vi = 0.0;
        if (lane == j) vi = ajj - alpha;
        else if (lane > j && lane < 15) vi = mj;
        double vtv = sig - 2.0*alpha*ajj + alpha*alpha;
        double tau = (vtv > 1e-300) ? (2.0 / vtv) : 0.0;
        #pragma unroll
        for (int c = 0; c < 7; ++c) {
            if (c >= j) {
                double s = wsum(vi * Mr[c]) * tau;
                Mr[c] -= s * vi;
            }
        }
        #pragma unroll
        for (int c = 0; c < 7; ++c) {
            double s = wsum(vi * Tr[c]) * tau;
            Tr[c] -= s * vi;
        }
        if (lane == j) Mr[j] = alpha;
        if (lane > j)  Mr[j] = 0.0;
    }

    __shared__ double Rs[7][7], Ts[7][7];
    if (lane < 7) {
        #pragma unroll
        for (int c = 0; c < 7; ++c) { Rs[lane][c] = Mr[c]; Ts[lane][c] = Tr[c]; }
    }
    __syncthreads();
    const int cc = (lane < 7) ? lane : 0;
    double xs[7];
    #pragma unroll
    for (int i = 6; i >= 0; --i) {
        double s = Ts[i][cc];
        #pragma unroll
        for (int k2 = 6; k2 > i; --k2) s -= Rs[i][k2] * xs[k2];
        xs[i] = s / Rs[i][i];
    }
    if (lane < 7) {
        #pragma unroll
        for (int i = 0; i < 7; ++i) bt[i*7 + lane] = (float)xs[i];
    }
    double rs[7];
    #pragma unroll
    for (int v = 0; v < 7; ++v)
        rs[v] = wsum((lane < 7) ? fabs(xs[v]) : 0.0);
    if (lane == 0) {
        double mb = 0.0;
        #pragma unroll
        for (int v = 0; v < 7; ++v) mb = fmax(mb, rs[v]);
        bt[49] = (mb * 128.0 <= 2048.0) ? 1.f : 0.f;
    }
}

// ---------------- Kernel 2: weight transform -> fp16 W[v][o][r][c] ----------------
__global__ void wt16_kernel(const float* __restrict__ w, _Float16* __restrict__ W) {
    int idx = blockIdx.x*256 + threadIdx.x;
    if (idx >= 7*COUT*3*CIN) return;
    int c = idx & 63;
    int r = (idx >> 6) % 3;
    int o = (idx / (64*3)) % COUT;
    int v = idx / (64*3*COUT);
    const float* wp = w + (((size_t)o*CIN + c)*3 + r)*3;
    const float Gf[7][3] = {{1,0,0},{1,1,1},{1,-1,1},{1,2,4},{1,-2,4},{1,3,9},{0,0,1}};
    float val = wp[0]*Gf[v][0] + wp[1]*Gf[v][1] + wp[2]*Gf[v][2];
    val = rintf(val);
    val = fminf(fmaxf(val, -32768.f), 32767.f);   // |val| <= 1664: exact fp16
    W[idx] = (_Float16)val;
}

// ---------------- Kernel 3: fused E-transform + MFMA GEMM + AT + epilogue ----------------
__device__ __forceinline__ void gload16(const void* g, void* l) {
    __builtin_amdgcn_global_load_lds((const __attribute__((address_space(1))) void*)g,
                                     (__attribute__((address_space(3))) void*)l, 16, 0, 0);
}

// E-compute for one v: 3 items/thread (t = q*4 + tid>>6, c = tid&63), 6 krows each.
#define E_COMPUTE(v) do { \
    const float b0 = bt[(v)*7+0], b1 = bt[(v)*7+1], b2 = bt[(v)*7+2], b3 = bt[(v)*7+3]; \
    const float b4 = bt[(v)*7+4], b5 = bt[(v)*7+5], b6 = bt[(v)*7+6]; \
    const float einit = -128.f*(b0+b1+b2+b3+b4+b5+b6); \
    _Pragma("unroll 1") \
    for (int q = 0; q < 3; ++q) { \
        const int t = q*4 + (tid >> 6); \
        _Pragma("unroll") \
        for (int krow = 0; krow < 6; ++krow) { \
            u64 wnd = *(const u64*)(lds + WINOFF + (krow*768 + q*256 + tid)*8); \
            u32 lo = (u32)wnd, hi = (u32)(wnd >> 32); \
            float e = einit; \
            e = fmaf(b0, (float)(lo & 255u),        e); \
            e = fmaf(b1, (float)((lo >> 8) & 255u), e); \
            e = fmaf(b2, (float)((lo >> 16) & 255u),e); \
            e = fmaf(b3, (float)(lo >> 24),         e); \
            e = fmaf(b4, (float)(hi & 255u),        e); \
            e = fmaf(b5, (float)((hi >> 8) & 255u), e); \
            e = fmaf(b6, (float)((hi >> 16) & 255u),e); \
            e = rintf(e); \
            e = fminf(fmaxf(e, -32768.f), 32767.f); \
            const int row = krow*12 + t; \
            const int sb = row*128 + ((((cc >> 3) ^ (row & 7)) << 4) | ((cc & 7) << 1)); \
            if (dual) { \
                float ehs = rintf(e * (1.f/2048.f)) * 2048.f; \
                *(_Float16*)(lds + EHOFF + sb) = (_Float16)ehs; \
                *(_Float16*)(lds + ELOFF + sb) = (_Float16)(e - ehs); \
            } else { \
                *(_Float16*)(lds + EHOFF + sb) = (_Float16)e; \
            } \
        } \
    } \
} while (0)

#define FOLD(v) do { \
    _Pragma("unroll") \
    for (int u = 0; u < 5; ++u) { \
        const float a = ATc[u][v]; \
        if (a != 0.f) { \
            _Pragma("unroll") \
            for (int f = 0; f < 9; ++f) yu[u*9+f] += a * mv[f]; \
        } \
    } \
    _Pragma("unroll") \
    for (int f = 0; f < 9; ++f) mv[f] = f32x4{0.f,0.f,0.f,0.f}; \
} while (0)

__global__ __launch_bounds__(256, 2)
void main_kernel(const float* __restrict__ x, const _Float16* __restrict__ W,
                 const float* __restrict__ bt,
                 const float* __restrict__ alpha, const float* __restrict__ beta,
                 const float* __restrict__ sfp, const float* __restrict__ sop,
                 float* __restrict__ out)
{
    extern __shared__ char lds[];
    const int kq = blockIdx.x, n = blockIdx.y, k0 = kq*KR;
    const int tid = threadIdx.x;
    const int lane = tid & 63, l15 = lane & 15, g = lane >> 4;
    const int ng = tid >> 6;                    // wave id = N-group (48 cols each)
    const int cc = tid & 63;                    // channel for E items
    const bool dual = (bt[49] < 0.5f);
    const int BOFF = dual ? 55296 : 46080;

    // ---- stage raw x rows (k0-1 .. k0+4) as biased u8, stride 68 ----
    #pragma unroll
    for (int j = 0; j < 21; ++j) {
        int idx = j*256 + tid;                   // < 5376 data words
        int row = idx / 14, w = idx - row*14;
        int krow = row >> 6, ch = row & 63;
        int xr = k0 + krow - 1;
        u32 bword = 0x80808080u;
        if (xr >= 0 && xr < HWD) {
            const float4 vx = *(const float4*)(x + (((size_t)(n*CIN + ch))*HWD + xr)*HWD + w*4);
            bword = (u32)(int)(vx.x + 128.f) | ((u32)(int)(vx.y + 128.f) << 8)
                  | ((u32)(int)(vx.z + 128.f) << 16) | ((u32)(int)(vx.w + 128.f) << 24);
        }
        *(u32*)(lds + RAWOFF + row*RAWSTR + 4 + w*4) = bword;
    }
    #pragma unroll
    for (int jj = 0; jj < 5; ++jj) {             // pads: bytes 0..3, 60..67
        int p = jj*256 + tid;
        if (p < 1152) {
            int row = p/3, ws = p - row*3;
            int wb = (ws == 0) ? 0 : (56 + ws*4);
            *(u32*)(lds + RAWOFF + row*RAWSTR + wb) = 0x80808080u;
        }
    }
    __syncthreads();

    // ---- build 8B-aligned window table: WIN[krow][item] = raw bytes 5t+3..5t+9 ----
    #pragma unroll 1
    for (int q = 0; q < 3; ++q) {
        int item = q*256 + tid;
        int t = item >> 6;
        int a0 = (5*t + 3) & ~7;
        int sh = ((5*t + 3) & 7) * 8;
        #pragma unroll
        for (int krow = 0; krow < 6; ++krow) {
            const char* pb = lds + RAWOFF + (krow*64 + cc)*RAWSTR + a0;
            u64 lo = *(const u64*)pb;
            u64 hi = *(const u64*)(pb + 8);
            u64 wnd = (lo >> sh) | ((hi << 1) << (63 - sh));
            *(u64*)(lds + WINOFF + (krow*768 + item)*8) = wnd;
        }
    }
    WAITL(); SBAR();                              // RAW dead; E/B regions free

    // ---- accumulators ----
    f32x4 yu[45], mv[9];
    #pragma unroll
    for (int f = 0; f < 45; ++f) yu[f] = f32x4{0.f,0.f,0.f,0.f};
    #pragma unroll
    for (int f = 0; f < 9; ++f) mv[f] = f32x4{0.f,0.f,0.f,0.f};

    const float ATc[5][7] = {
        {1,1,1,1,1,1,0},{0,1,-1,2,-2,3,0},{0,1,1,4,4,9,0},{0,1,-1,8,-8,27,0},{0,1,1,16,16,81,1}};

    const int boffB0 = (ng*48 +  0 + l15)*64 + g*16;
    const int boffB1 = (ng*48 + 16 + l15)*64 + g*16;
    const int boffB2 = (ng*48 + 32 + l15)*64 + g*16;

    auto STAGE = [&](int S){
        int v = S/6, rem = S - v*6, rr = rem >> 1, chh = rem & 1;
        #pragma unroll
        for (int q2 = 0; q2 < 3; ++q2) {
            int chunk = q2*256 + tid;
            int o = chunk >> 2, cq = chunk & 3;
            const _Float16* src = W + (((v*COUT + o)*3 + rr) << 6) + chh*32 + cq*8;
            gload16(src, lds + BOFF + (S & 1)*12288 + chunk*16);
        }
    };

    // prologue: stage buf0; compute E(0) under the load latency
    STAGE(0);
    E_COMPUTE(0);
    WAITVL0(); SBAR();

    #pragma unroll
    for (int v = 0; v < 7; ++v) {
        if (v > 0) {
            FOLD(v-1);
            E_COMPUTE(v);
            WAITL(); SBAR();
        }
        #pragma unroll 1
        for (int si = 0; si < 6; ++si) {
            const int S = v*6 + si;
            if (S < 41) STAGE(S + 1);
            const int rr = si >> 1, chh = si & 1;
            const char* bb = lds + BOFF + (S & 1)*12288;
            f16x8 bf0 = *(const f16x8*)(bb + boffB0);
            f16x8 bf1 = *(const f16x8*)(bb + boffB1);
            f16x8 bf2 = *(const f16x8*)(bb + boffB2);
            __builtin_amdgcn_s_setprio(1);
            #pragma unroll
            for (int ai = 0; ai < 3; ++ai) {
                const int arow = rr*12 + ai*16 + l15;
                const int ab = arow*128 + ((((chh << 2) | g) ^ (arow & 7)) << 4);
                f16x8 ah = *(const f16x8*)(lds + EHOFF + ab);
                mv[ai*3+0] = __builtin_amdgcn_mfma_f32_16x16x32_f16(ah, bf0, mv[ai*3+0], 0,0,0);
                mv[ai*3+1] = __builtin_amdgcn_mfma_f32_16x16x32_f16(ah, bf1, mv[ai*3+1], 0,0,0);
                mv[ai*3+2] = __builtin_amdgcn_mfma_f32_16x16x32_f16(ah, bf2, mv[ai*3+2], 0,0,0);
            }
            if (dual) {
                #pragma unroll
                for (int ai = 0; ai < 3; ++ai) {
                    const int arow = rr*12 + ai*16 + l15;
                    const int ab = arow*128 + ((((chh << 2) | g) ^ (arow & 7)) << 4);
                    f16x8 al = *(const f16x8*)(lds + ELOFF + ab);
                    mv[ai*3+0] = __builtin_amdgcn_mfma_f32_16x16x32_f16(al, bf0, mv[ai*3+0], 0,0,0);
                    mv[ai*3+1] = __builtin_amdgcn_mfma_f32_16x16x32_f16(al, bf1, mv[ai*3+1], 0,0,0);
                    mv[ai*3+2] = __builtin_amdgcn_mfma_f32_16x16x32_f16(al, bf2, mv[ai*3+2], 0,0,0);
                }
            }
            __builtin_amdgcn_s_setprio(0);
            // own prefetch drained BEFORE barrier -> buffer globally ready next step
            WAITV0(); SBAR();
        }
    }
    FOLD(6);

    // ---- epilogue: quantize to u8 in LDS (overlay WIN/E, all reads retired), coalesced out ----
    const float rdenom = 1.f / (120.f * sfp[0]);
    float av0 = alpha[ng*48 +  0 + l15], av1 = alpha[ng*48 + 16 + l15], av2 = alpha[ng*48 + 32 + l15];
    float be0 = rintf(beta[ng*48 +  0 + l15] * sop[0]);
    float be1 = rintf(beta[ng*48 + 16 + l15] * sop[0]);
    float be2 = rintf(beta[ng*48 + 32 + l15] * sop[0]);
    unsigned char* ldsb = (unsigned char*)lds;    // [192][224]
    #pragma unroll
    for (int ai = 0; ai < 3; ++ai) {
        #pragma unroll
        for (int q = 0; q < 4; ++q) {
            const int m = ai*16 + g*4 + q;        // 0..47
            const int kl = m / 12, t = m - kl*12;
            #pragma unroll
            for (int bj = 0; bj < 3; ++bj) {
                const int o = ng*48 + bj*16 + l15;
                const float avv = (bj == 0) ? av0 : (bj == 1) ? av1 : av2;
                const float bev = (bj == 0) ? be0 : (bj == 1) ? be1 : be2;
                #pragma unroll
                for (int u = 0; u < 5; ++u) {
                    const int col = t*5 + u;
                    if (col < HWD) {
                        float yv = yu[u*9 + ai*3 + bj][q];
                        yv = rintf(yv * rdenom);
                        yv = rintf(avv*yv) + bev;
                        yv = rintf(yv);
                        yv = fminf(fmaxf(yv, -128.f), 127.f);
                        yv = fmaxf(yv, 0.f);
                        ldsb[o*224 + kl*56 + col] = (unsigned char)(int)yv;
                    }
                }
            }
        }
    }
    __syncthreads();
    float* ob = out + ((size_t)(n*COUT))*3136 + k0*56;
    #pragma unroll 1
    for (int it = 0; it < 42; ++it) {
        int i = it*256 + tid;                     // < 10752 quads
        int o = i / 56, q4 = i - o*56;
        u32 wb2 = *(const u32*)(ldsb + o*224 + q4*4);
        float4 f;
        f.x = (float)(wb2 & 255u);
        f.y = (float)((wb2 >> 8) & 255u);
        f.z = (float)((wb2 >> 16) & 255u);
        f.w = (float)(wb2 >> 24);
        *(float4*)(ob + (size_t)o*3136 + q4*4) = f;
    }
}

extern "C" void kernel_launch(void* const* d_in, const int* in_sizes, int n_in,
                              void* d_out, int out_size, void* d_ws, size_t ws_size,
                              hipStream_t stream) {
    const float* x      = (const float*)d_in[0];
    const float* weight = (const float*)d_in[1];
    const float* alpha  = (const float*)d_in[2];
    const float* beta   = (const float*)d_in[3];
    const float* sf     = (const float*)d_in[4];
    const float* so     = (const float*)d_in[5];
    float* out = (float*)d_out;

    float* ws_bt = (float*)((char*)d_ws + WS_BT_OFF);
    _Float16* Wp = (_Float16*)((char*)d_ws + WS_W_OFF);

    (void)hipFuncSetAttribute((const void*)main_kernel,
                              hipFuncAttributeMaxDynamicSharedMemorySize, LDS_TOTAL);

    compute_bt_kernel<<<1, 64, 0, stream>>>(ws_bt);
    wt16_kernel<<<(7*COUT*3*CIN + 255)/256, 256, 0, stream>>>(weight, Wp);
    main_kernel<<<dim3(NKQ, NBATCH), 256, LDS_TOTAL, stream>>>(x, Wp, ws_bt, alpha, beta, sf, so, out);
}